// Round 2
// baseline (696.358 us; speedup 1.0000x reference)
//
#include <hip/hip_runtime.h>
#include <math.h>

// Problem constants (fixed by the reference: N=16384, H=16, C=32, NE=196608)
#define H_DIM 16
#define C_DIM 32
#define HC_DIM (H_DIM * C_DIM)   // 512
#define EPSF 1e-5f

__device__ __forceinline__ float reduce8(float x) {
    // sum across the 8 lanes that share one head; lanes are contiguous within
    // a 64-lane wave, so xor masks 1/2/4 never cross the wave boundary.
    x += __shfl_xor(x, 1);
    x += __shfl_xor(x, 2);
    x += __shfl_xor(x, 4);
    return x;
}

// Nontemporal float4 load via clang ext_vector (float4 itself is a struct).
typedef float f4_raw __attribute__((ext_vector_type(4)));
__device__ __forceinline__ float4 nt_load4(const float* p) {
    f4_raw r = __builtin_nontemporal_load((const f4_raw*)p);
    return make_float4(r.x, r.y, r.z, r.w);
}
__device__ __forceinline__ void nt_store4(float* p, float4 v) {
    f4_raw r = {v.x, v.y, v.z, v.w};
    __builtin_nontemporal_store(r, (f4_raw*)p);
}

__global__ void zero_kernel(int* __restrict__ p, int n) {
    int i = blockIdx.x * blockDim.x + threadIdx.x;
    if (i < n) p[i] = 0;
}

__global__ void hist_kernel(const int* __restrict__ edst, int* __restrict__ counts, int ne) {
    int i = blockIdx.x * blockDim.x + threadIdx.x;
    if (i < ne) atomicAdd(&counts[edst[i]], 1);
}

// Precompute kinv[n*H + h] = rsqrt(mean(k[n,h,:]^2) + eps).
// 8 lanes per (n,h) row, each handling a float4 of C=32.
__global__ void kinv_kernel(const float* __restrict__ k, float* __restrict__ kinv, int rows) {
    int gt = blockIdx.x * blockDim.x + threadIdx.x;
    int row = gt >> 3;
    if (row < rows) {
        const float4 kv = *(const float4*)(k + (size_t)row * C_DIM + ((gt & 7) << 2));
        float s = kv.x * kv.x + kv.y * kv.y + kv.z * kv.z + kv.w * kv.w;
        s = reduce8(s);
        if ((gt & 7) == 0) kinv[row] = rsqrtf(s * (1.0f / C_DIM) + EPSF);
    }
}

// Single-block exclusive scan over counts[n] -> offsets[n+1].
__global__ __launch_bounds__(1024)
void scan_kernel(const int* __restrict__ counts, int* __restrict__ offsets, int n) {
    __shared__ int wsum[16];
    __shared__ int carry_s;
    const int tid = threadIdx.x;
    const int lane = tid & 63;
    const int wid = tid >> 6;
    if (tid == 0) { carry_s = 0; offsets[0] = 0; }
    __syncthreads();
    for (int base = 0; base < n; base += 1024) {
        int x = (base + tid < n) ? counts[base + tid] : 0;
        int v = x;
        #pragma unroll
        for (int off = 1; off < 64; off <<= 1) {
            int y = __shfl_up(v, off);
            if (lane >= off) v += y;
        }
        if (lane == 63) wsum[wid] = v;
        __syncthreads();
        if (wid == 0 && lane < 16) {
            int s = wsum[lane];
            #pragma unroll
            for (int off = 1; off < 16; off <<= 1) {
                int y = __shfl_up(s, off);
                if (lane >= off) s += y;
            }
            wsum[lane] = s;
        }
        __syncthreads();
        int waveoff = (wid == 0) ? 0 : wsum[wid - 1];
        int carry = carry_s;
        if (base + tid < n) offsets[base + tid + 1] = carry + waveoff + v;
        __syncthreads();
        if (tid == 1023) carry_s = carry + wsum[15];
        __syncthreads();
    }
}

__global__ void scatter_kernel(const int* __restrict__ esrc, const int* __restrict__ edst,
                               const int* __restrict__ offsets, int* __restrict__ cursor,
                               int2* __restrict__ perm, int ne) {
    int i = blockIdx.x * blockDim.x + threadIdx.x;
    if (i < ne) {
        int d = edst[i];
        int pos = offsets[d] + atomicAdd(&cursor[d], 1);
        perm[pos] = make_int2(esrc[i], i);  // {src, eid}
    }
}

// Per-edge data held in flight (registers).
struct EdgeData {
    float4 ev, kv, vv;
    float  ki;
};

__device__ __forceinline__ EdgeData load_edge(int2 p,
                                              const float* __restrict__ e,
                                              const float* __restrict__ k,
                                              const float* __restrict__ v,
                                              const float* __restrict__ kinv,
                                              int hc, int h) {
    EdgeData d;
    // e is single-use (403 MB/pass): nontemporal so it doesn't evict k/v from L3.
    d.ev = nt_load4(e + (size_t)p.y * HC_DIM + hc);
    d.kv = *(const float4*)(k + p.x * HC_DIM + hc);
    d.vv = *(const float4*)(v + p.x * HC_DIM + hc);
    d.ki = kinv[p.x * H_DIM + h];   // broadcast within 8-lane group; 1 MB table, L2-hot
    return d;
}

// Online-softmax update given already-loaded edge data. kinv precomputed, so no
// cross-lane reduce on the k-norm path.
__device__ __forceinline__ void update_edge(const EdgeData& d,
                                            float4 qn, float4 wkv, float qk_scale,
                                            float& m, float& l, float4& acc) {
    float kex = d.kv.x * (d.ki * wkv.x) + d.ev.x;
    float key = d.kv.y * (d.ki * wkv.y) + d.ev.y;
    float kez = d.kv.z * (d.ki * wkv.z) + d.ev.z;
    float kew = d.kv.w * (d.ki * wkv.w) + d.ev.w;
    float dd = qn.x * kex + qn.y * key + qn.z * kez + qn.w * kew;
    dd = reduce8(dd);
    float s = dd * qk_scale;
    float mnew = fmaxf(m, s);
    float sc = __expf(m - mnew);   // first edge: exp(-inf) = 0
    float al = __expf(s - mnew);
    l = l * sc + al;
    acc.x = acc.x * sc + al * (d.vv.x + d.ev.x);
    acc.y = acc.y * sc + al * (d.vv.y + d.ev.y);
    acc.z = acc.z * sc + al * (d.vv.z + d.ev.z);
    acc.w = acc.w * sc + al * (d.vv.w + d.ev.w);
    m = mnew;
}

// One block per dst node. 128 threads = 16 heads x 8 lanes; each lane owns a
// float4 of the C=32 channel dim. Two independent online-softmax streams
// (merged at the end), each with a 1-deep explicit gather pipeline, plus the
// perm (edge index) entries carried one further iteration ahead so the scalar
// perm load never sits in front of the gathers on the critical path.
__global__ __launch_bounds__(128, 4)
void attn_kernel(const float* __restrict__ q, const float* __restrict__ k,
                 const float* __restrict__ v, const float* __restrict__ e,
                 const float* __restrict__ wq, const float* __restrict__ wk,
                 const float* __restrict__ kinv,
                 const int* __restrict__ offsets, const int2* __restrict__ perm,
                 float* __restrict__ out)
{
    const int node = blockIdx.x;
    const int t = threadIdx.x;
    const int hc = t << 2;             // h*C + c4 == 4*t
    const int c4 = (t & 7) << 2;
    const int h  = t >> 3;
    const float qk_scale = 0.17677669529663687f;  // 1/sqrt(32)

    const int node_off = node * HC_DIM + hc;

    // fused q RMSNorm (once per node)
    float4 qv = *(const float4*)(q + node_off);
    float qs = qv.x * qv.x + qv.y * qv.y + qv.z * qv.z + qv.w * qv.w;
    qs = reduce8(qs);
    float qinv = rsqrtf(qs * (1.0f / C_DIM) + EPSF);
    float4 wqv = *(const float4*)(wq + c4);
    float4 qn = make_float4(qv.x * qinv * wqv.x, qv.y * qinv * wqv.y,
                            qv.z * qinv * wqv.z, qv.w * qinv * wqv.w);
    float4 wkv = *(const float4*)(wk + c4);

    const int row0 = offsets[node];
    const int row1 = offsets[node + 1];
    const int len = row1 - row0;
    const int mid = row0 + ((len + 1) >> 1);

    float mA = -INFINITY, lA = 0.0f, mB = -INFINITY, lB = 0.0f;
    float4 accA = make_float4(0.f, 0.f, 0.f, 0.f);
    float4 accB = make_float4(0.f, 0.f, 0.f, 0.f);

    int jA = row0, jB = mid;
    if (jB < row1) {                 // len >= 2: both streams non-empty
        int2 pA = perm[jA];
        int2 pB = perm[jB];
        EdgeData a = load_edge(pA, e, k, v, kinv, hc, h);
        EdgeData b = load_edge(pB, e, k, v, kinv, hc, h);
        ++jA; ++jB;
        // perm entries for the NEXT pair, carried one iteration ahead
        bool haveNext = (jB < row1);
        int2 nA, nB;
        if (haveNext) { nA = perm[jA]; nB = perm[jB]; }
        while (haveNext) {
            // issue next pair's gathers (addresses already in registers)
            EdgeData a2 = load_edge(nA, e, k, v, kinv, hc, h);
            EdgeData b2 = load_edge(nB, e, k, v, kinv, hc, h);
            ++jA; ++jB;
            haveNext = (jB < row1);
            if (haveNext) { nA = perm[jA]; nB = perm[jB]; }  // overlaps the updates below
            update_edge(a, qn, wkv, qk_scale, mA, lA, accA);
            update_edge(b, qn, wkv, qk_scale, mB, lB, accB);
            a = a2; b = b2;
        }
        update_edge(a, qn, wkv, qk_scale, mA, lA, accA);
        update_edge(b, qn, wkv, qk_scale, mB, lB, accB);
    }
    while (jA < mid) {   // at most one extra edge (lenA = lenB or lenB+1), or len==1
        int2 p = perm[jA];
        EdgeData a = load_edge(p, e, k, v, kinv, hc, h);
        update_edge(a, qn, wkv, qk_scale, mA, lA, accA);
        ++jA;
    }

    // merge the two streams (guard exp(-inf - -inf) = NaN for empty streams)
    float M = fmaxf(mA, mB);
    float fA = (lA > 0.0f) ? __expf(mA - M) : 0.0f;
    float fB = (lB > 0.0f) ? __expf(mB - M) : 0.0f;
    float l = lA * fA + lB * fB;
    float4 acc = make_float4(accA.x * fA + accB.x * fB,
                             accA.y * fA + accB.y * fB,
                             accA.z * fA + accB.z * fB,
                             accA.w * fA + accB.w * fB);

    float invl = (l > 0.0f) ? (1.0f / l) : 0.0f;  // empty rows -> 0 (matches ref)
    nt_store4(out + node_off, make_float4(acc.x * invl, acc.y * invl,
                                          acc.z * invl, acc.w * invl));
}

extern "C" void kernel_launch(void* const* d_in, const int* in_sizes, int n_in,
                              void* d_out, int out_size, void* d_ws, size_t ws_size,
                              hipStream_t stream) {
    const float* q  = (const float*)d_in[0];
    const float* k  = (const float*)d_in[1];
    const float* v  = (const float*)d_in[2];
    const float* e  = (const float*)d_in[3];
    const float* wq = (const float*)d_in[4];
    const float* wk = (const float*)d_in[5];
    const int* esrc = (const int*)d_in[6];
    const int* edst = (const int*)d_in[7];
    float* out = (float*)d_out;

    const int NE = in_sizes[6];
    const int HC = in_sizes[3] / NE;      // H*C (derivation identical to verified kernel)
    const int N  = in_sizes[0] / HC;      // 16384

    // workspace layout:
    //   perm[NE] (int2, 8B-aligned first) | counts[N] | cursor[N] | offsets[N+1] | kinv[N*H]
    int2* perm    = (int2*)d_ws;
    int* counts   = (int*)(perm + NE);
    int* cursor   = counts + N;
    int* offsets  = cursor + N;
    float* kinv   = (float*)(offsets + N + 1);

    const int rows = N * H_DIM;

    zero_kernel<<<(2 * N + 255) / 256, 256, 0, stream>>>(counts, 2 * N);
    hist_kernel<<<(NE + 255) / 256, 256, 0, stream>>>(edst, counts, NE);
    kinv_kernel<<<(rows * 8 + 255) / 256, 256, 0, stream>>>(k, kinv, rows);
    scan_kernel<<<1, 1024, 0, stream>>>(counts, offsets, N);
    scatter_kernel<<<(NE + 255) / 256, 256, 0, stream>>>(esrc, edst, offsets, cursor,
                                                         perm, NE);
    attn_kernel<<<N, 128, 0, stream>>>(q, k, v, e, wq, wk, kinv, offsets, perm, out);
}

// Round 4
// 685.851 us; speedup vs baseline: 1.0153x; 1.0153x over previous
//
#include <hip/hip_runtime.h>
#include <math.h>

// Problem constants (fixed by the reference: N=16384, H=16, C=32, NE=196608)
#define H_DIM 16
#define C_DIM 32
#define HC_DIM (H_DIM * C_DIM)   // 512
#define EPSF 1e-5f

__device__ __forceinline__ float reduce8(float x) {
    // sum across the 8 lanes that share one head; lanes are contiguous within
    // a 64-lane wave, so xor masks 1/2/4 never cross the wave boundary.
    x += __shfl_xor(x, 1);
    x += __shfl_xor(x, 2);
    x += __shfl_xor(x, 4);
    return x;
}

// Nontemporal float4 load via clang ext_vector (float4 itself is a struct).
typedef float f4_raw __attribute__((ext_vector_type(4)));
__device__ __forceinline__ float4 nt_load4(const float* p) {
    f4_raw r = __builtin_nontemporal_load((const f4_raw*)p);
    return make_float4(r.x, r.y, r.z, r.w);
}
__device__ __forceinline__ void nt_store4(float* p, float4 v) {
    f4_raw r = {v.x, v.y, v.z, v.w};
    __builtin_nontemporal_store(r, (f4_raw*)p);
}

__global__ void zero_kernel(int* __restrict__ p, int n) {
    int i = blockIdx.x * blockDim.x + threadIdx.x;
    if (i < n) p[i] = 0;
}

// Fused: blocks [0, histBlocks) do the dst histogram (4 edges per thread via
// int4); the rest compute kinv[n*H + h] = rsqrt(mean(k[n,h,:]^2) + eps) with
// 8 lanes per row. Disjoint data -> one launch replaces two.
__global__ __launch_bounds__(256)
void hist_kinv_kernel(const int* __restrict__ edst, int* __restrict__ counts,
                      const float* __restrict__ k, float* __restrict__ kinv,
                      int ne, int rows, int histBlocks) {
    if ((int)blockIdx.x < histBlocks) {
        int i4 = (blockIdx.x * 256 + threadIdx.x) * 4;
        if (i4 + 4 <= ne) {
            int4 d = *(const int4*)(edst + i4);
            atomicAdd(&counts[d.x], 1);
            atomicAdd(&counts[d.y], 1);
            atomicAdd(&counts[d.z], 1);
            atomicAdd(&counts[d.w], 1);
        } else {
            for (int j = i4; j < ne; ++j) atomicAdd(&counts[edst[j]], 1);
        }
    } else {
        int gt = (blockIdx.x - histBlocks) * 256 + threadIdx.x;
        int row = gt >> 3;
        if (row < rows) {
            const float4 kv = *(const float4*)(k + (size_t)row * C_DIM + ((gt & 7) << 2));
            float s = kv.x * kv.x + kv.y * kv.y + kv.z * kv.z + kv.w * kv.w;
            s = reduce8(s);
            if ((gt & 7) == 0) kinv[row] = rsqrtf(s * (1.0f / C_DIM) + EPSF);
        }
    }
}

// Single-block exclusive scan over counts[n] -> offsets[n+1].
// 16 ints per thread (int4 x4), one wave scan + one 16-wave scan:
// 2 barriers per 16384-chunk (vs 64 barriers total in the old version).
__global__ __launch_bounds__(1024)
void scan_kernel(const int* __restrict__ counts, int* __restrict__ offsets, int n) {
    __shared__ int wsum[16];
    __shared__ int carry_s;
    const int tid = threadIdx.x;
    const int lane = tid & 63;
    const int wid = tid >> 6;
    if (tid == 0) carry_s = 0;
    __syncthreads();
    for (int b0 = 0; b0 < n; b0 += 16384) {
        const int base = b0 + tid * 16;
        int c[16];
        if (base + 16 <= n) {
            const int4* p = (const int4*)(counts + base);
            int4 t0 = p[0], t1 = p[1], t2 = p[2], t3 = p[3];
            c[0]=t0.x; c[1]=t0.y; c[2]=t0.z; c[3]=t0.w;
            c[4]=t1.x; c[5]=t1.y; c[6]=t1.z; c[7]=t1.w;
            c[8]=t2.x; c[9]=t2.y; c[10]=t2.z; c[11]=t2.w;
            c[12]=t3.x; c[13]=t3.y; c[14]=t3.z; c[15]=t3.w;
        } else {
            #pragma unroll
            for (int j = 0; j < 16; ++j) c[j] = (base + j < n) ? counts[base + j] : 0;
        }
        int s = 0;
        #pragma unroll
        for (int j = 0; j < 16; ++j) s += c[j];
        // inclusive wave scan of per-thread sums
        int v = s;
        #pragma unroll
        for (int off = 1; off < 64; off <<= 1) {
            int y = __shfl_up(v, off);
            if (lane >= off) v += y;
        }
        if (lane == 63) wsum[wid] = v;
        __syncthreads();
        if (wid == 0 && lane < 16) {
            int w = wsum[lane];
            #pragma unroll
            for (int off = 1; off < 16; off <<= 1) {
                int y = __shfl_up(w, off);
                if (lane >= off) w += y;
            }
            wsum[lane] = w;
        }
        __syncthreads();
        const int carry = carry_s;
        int p = carry + (wid ? wsum[wid - 1] : 0) + (v - s);  // exclusive prefix
        int o[16];
        #pragma unroll
        for (int j = 0; j < 16; ++j) { o[j] = p; p += c[j]; }
        if (base + 16 <= n) {
            int4* q = (int4*)(offsets + base);
            q[0] = make_int4(o[0], o[1], o[2], o[3]);
            q[1] = make_int4(o[4], o[5], o[6], o[7]);
            q[2] = make_int4(o[8], o[9], o[10], o[11]);
            q[3] = make_int4(o[12], o[13], o[14], o[15]);
        } else {
            #pragma unroll
            for (int j = 0; j < 16; ++j)
                if (base + j < n) offsets[base + j] = o[j];
        }
        if (n - 1 >= base && n - 1 < base + 16) offsets[n] = p;  // grand total
        __syncthreads();   // all reads of carry_s/wsum done
        if (tid == 0) carry_s = carry + wsum[15];
        __syncthreads();
    }
}

// 4 edges per thread via int4 loads of esrc/edst; atomic count unchanged.
__global__ void scatter_kernel(const int* __restrict__ esrc, const int* __restrict__ edst,
                               const int* __restrict__ offsets, int* __restrict__ cursor,
                               int2* __restrict__ perm, int ne) {
    int i4 = (blockIdx.x * blockDim.x + threadIdx.x) * 4;
    if (i4 + 4 <= ne) {
        int4 d = *(const int4*)(edst + i4);
        int4 s = *(const int4*)(esrc + i4);
        int p0 = offsets[d.x] + atomicAdd(&cursor[d.x], 1);
        perm[p0] = make_int2(s.x, i4 + 0);
        int p1 = offsets[d.y] + atomicAdd(&cursor[d.y], 1);
        perm[p1] = make_int2(s.y, i4 + 1);
        int p2 = offsets[d.z] + atomicAdd(&cursor[d.z], 1);
        perm[p2] = make_int2(s.z, i4 + 2);
        int p3 = offsets[d.w] + atomicAdd(&cursor[d.w], 1);
        perm[p3] = make_int2(s.w, i4 + 3);
    } else {
        for (int j = i4; j < ne; ++j) {
            int d = edst[j];
            int pos = offsets[d] + atomicAdd(&cursor[d], 1);
            perm[pos] = make_int2(esrc[j], j);
        }
    }
}

// Per-edge data held in flight (registers).
struct EdgeData {
    float4 ev, kv, vv;
    float  ki;
};

__device__ __forceinline__ EdgeData load_edge(int2 p,
                                              const float* __restrict__ e,
                                              const float* __restrict__ k,
                                              const float* __restrict__ v,
                                              const float* __restrict__ kinv,
                                              int hc, int h) {
    EdgeData d;
    // e is single-use (403 MB/pass): nontemporal so it doesn't evict k/v from L3.
    d.ev = nt_load4(e + (size_t)p.y * HC_DIM + hc);
    d.kv = *(const float4*)(k + p.x * HC_DIM + hc);
    d.vv = *(const float4*)(v + p.x * HC_DIM + hc);
    d.ki = kinv[p.x * H_DIM + h];   // broadcast within 8-lane group; 1 MB table, L2-hot
    return d;
}

// Online-softmax update. qnw = qn*wk*scale, qns = qn*scale folded per node, so
// the per-edge dependent chain is: 2 short dots -> 1 fma -> reduce8 -> exp.
__device__ __forceinline__ void update_edge(const EdgeData& d,
                                            float4 qnw, float4 qns,
                                            float& m, float& l, float4& acc) {
    float dk = qnw.x * d.kv.x + qnw.y * d.kv.y + qnw.z * d.kv.z + qnw.w * d.kv.w;
    float de = qns.x * d.ev.x + qns.y * d.ev.y + qns.z * d.ev.z + qns.w * d.ev.w;
    float s = reduce8(dk * d.ki + de);
    float mnew = fmaxf(m, s);
    float sc = __expf(m - mnew);   // first edge: exp(-inf) = 0
    float al = __expf(s - mnew);
    l = l * sc + al;
    acc.x = acc.x * sc + al * (d.vv.x + d.ev.x);
    acc.y = acc.y * sc + al * (d.vv.y + d.ev.y);
    acc.z = acc.z * sc + al * (d.vv.z + d.ev.z);
    acc.w = acc.w * sc + al * (d.vv.w + d.ev.w);
    m = mnew;
}

// One block per dst node. 128 threads = 16 heads x 8 lanes; each lane owns a
// float4 of the C=32 channel dim. Two independent online-softmax streams
// (merged at the end), each with a 1-deep explicit gather pipeline, plus the
// perm entries carried one further iteration ahead so the perm load never
// fronts the gathers on the critical path.
__global__ __launch_bounds__(128, 4)
void attn_kernel(const float* __restrict__ q, const float* __restrict__ k,
                 const float* __restrict__ v, const float* __restrict__ e,
                 const float* __restrict__ wq, const float* __restrict__ wk,
                 const float* __restrict__ kinv,
                 const int* __restrict__ offsets, const int2* __restrict__ perm,
                 float* __restrict__ out)
{
    const int node = blockIdx.x;
    const int t = threadIdx.x;
    const int hc = t << 2;             // h*C + c4 == 4*t
    const int c4 = (t & 7) << 2;
    const int h  = t >> 3;
    const float qk_scale = 0.17677669529663687f;  // 1/sqrt(32)

    const int node_off = node * HC_DIM + hc;

    // fused q RMSNorm (once per node); q is single-use -> nontemporal
    float4 qv = nt_load4(q + node_off);
    float qs = qv.x * qv.x + qv.y * qv.y + qv.z * qv.z + qv.w * qv.w;
    qs = reduce8(qs);
    float qinv = rsqrtf(qs * (1.0f / C_DIM) + EPSF);
    float4 wqv = *(const float4*)(wq + c4);
    float4 wkv = *(const float4*)(wk + c4);
    // qn = qv*qinv*wqv; fold wk and qk_scale in per-node vectors:
    float4 qn = make_float4(qv.x * qinv * wqv.x, qv.y * qinv * wqv.y,
                            qv.z * qinv * wqv.z, qv.w * qinv * wqv.w);
    float4 qnw = make_float4(qn.x * wkv.x * qk_scale, qn.y * wkv.y * qk_scale,
                             qn.z * wkv.z * qk_scale, qn.w * wkv.w * qk_scale);
    float4 qns = make_float4(qn.x * qk_scale, qn.y * qk_scale,
                             qn.z * qk_scale, qn.w * qk_scale);

    const int row0 = offsets[node];
    const int row1 = offsets[node + 1];
    const int len = row1 - row0;
    const int mid = row0 + ((len + 1) >> 1);

    float mA = -INFINITY, lA = 0.0f, mB = -INFINITY, lB = 0.0f;
    float4 accA = make_float4(0.f, 0.f, 0.f, 0.f);
    float4 accB = make_float4(0.f, 0.f, 0.f, 0.f);

    int jA = row0, jB = mid;
    if (jB < row1) {                 // len >= 2: both streams non-empty
        int2 pA = perm[jA];
        int2 pB = perm[jB];
        EdgeData a = load_edge(pA, e, k, v, kinv, hc, h);
        EdgeData b = load_edge(pB, e, k, v, kinv, hc, h);
        ++jA; ++jB;
        bool haveNext = (jB < row1);
        int2 nA, nB;
        if (haveNext) { nA = perm[jA]; nB = perm[jB]; }
        while (haveNext) {
            EdgeData a2 = load_edge(nA, e, k, v, kinv, hc, h);
            EdgeData b2 = load_edge(nB, e, k, v, kinv, hc, h);
            ++jA; ++jB;
            haveNext = (jB < row1);
            if (haveNext) { nA = perm[jA]; nB = perm[jB]; }  // overlaps the updates
            update_edge(a, qnw, qns, mA, lA, accA);
            update_edge(b, qnw, qns, mB, lB, accB);
            a = a2; b = b2;
        }
        update_edge(a, qnw, qns, mA, lA, accA);
        update_edge(b, qnw, qns, mB, lB, accB);
    }
    while (jA < mid) {   // at most one extra edge (lenA = lenB or lenB+1), or len==1
        int2 p = perm[jA];
        EdgeData a = load_edge(p, e, k, v, kinv, hc, h);
        update_edge(a, qnw, qns, mA, lA, accA);
        ++jA;
    }

    // merge the two streams (guard exp(-inf - -inf) = NaN for empty streams)
    float M = fmaxf(mA, mB);
    float fA = (lA > 0.0f) ? __expf(mA - M) : 0.0f;
    float fB = (lB > 0.0f) ? __expf(mB - M) : 0.0f;
    float l = lA * fA + lB * fB;
    float4 acc = make_float4(accA.x * fA + accB.x * fB,
                             accA.y * fA + accB.y * fB,
                             accA.z * fA + accB.z * fB,
                             accA.w * fA + accB.w * fB);

    float invl = (l > 0.0f) ? (1.0f / l) : 0.0f;  // empty rows -> 0 (matches ref)
    nt_store4(out + node_off, make_float4(acc.x * invl, acc.y * invl,
                                          acc.z * invl, acc.w * invl));
}

extern "C" void kernel_launch(void* const* d_in, const int* in_sizes, int n_in,
                              void* d_out, int out_size, void* d_ws, size_t ws_size,
                              hipStream_t stream) {
    const float* q  = (const float*)d_in[0];
    const float* k  = (const float*)d_in[1];
    const float* v  = (const float*)d_in[2];
    const float* e  = (const float*)d_in[3];
    const float* wq = (const float*)d_in[4];
    const float* wk = (const float*)d_in[5];
    const int* esrc = (const int*)d_in[6];
    const int* edst = (const int*)d_in[7];
    float* out = (float*)d_out;

    const int NE = in_sizes[6];
    const int HC = in_sizes[3] / NE;      // H*C
    const int N  = in_sizes[0] / HC;      // 16384

    // workspace layout:
    //   perm[NE] (int2, 8B-aligned first) | counts[N] | cursor[N] | offsets[N+1] | kinv[N*H]
    int2* perm    = (int2*)d_ws;
    int* counts   = (int*)(perm + NE);
    int* cursor   = counts + N;
    int* offsets  = cursor + N;
    float* kinv   = (float*)(offsets + N + 1);

    const int rows = N * H_DIM;
    const int histBlocks = (NE / 4 + 255) / 256;        // 4 edges per thread
    const int kinvBlocks = (rows * 8 + 255) / 256;
    const int scatBlocks = (NE / 4 + 255) / 256;

    zero_kernel<<<(2 * N + 255) / 256, 256, 0, stream>>>(counts, 2 * N);
    hist_kinv_kernel<<<histBlocks + kinvBlocks, 256, 0, stream>>>(edst, counts, k, kinv,
                                                                  NE, rows, histBlocks);
    scan_kernel<<<1, 1024, 0, stream>>>(counts, offsets, N);
    scatter_kernel<<<scatBlocks, 256, 0, stream>>>(esrc, edst, offsets, cursor,
                                                   perm, NE);
    attn_kernel<<<N, 128, 0, stream>>>(q, k, v, e, wq, wk, kinv, offsets, perm, out);
}